// Round 7
// baseline (237.836 us; speedup 1.0000x reference)
//
#include <hip/hip_runtime.h>
#include <hip/hip_bf16.h>

typedef __attribute__((ext_vector_type(8))) short short8v;
typedef __attribute__((ext_vector_type(4))) float float4v;
typedef __attribute__((ext_vector_type(4))) unsigned uint4v;

__device__ __forceinline__ unsigned short f2bf(float x) {
    unsigned u = __float_as_uint(x);
    unsigned r = (u + 0x7fffu + ((u >> 16) & 1u)) >> 16;
    return (unsigned short)r;
}
__device__ __forceinline__ float bf2f(unsigned short u) {
    return __uint_as_float((unsigned)u << 16);
}
__device__ __forceinline__ unsigned cvt_pk_bf16(float lo, float hi) {
    unsigned r;
    asm("v_cvt_pk_bf16_f32 %0, %1, %2" : "=v"(r) : "v"(lo), "v"(hi));
    return r;
}

// ---------- branch 1x1 conv + BN + ReLU (a4: CIN=128, a32: CIN=256) ----------
template<int CIN>
__global__ __launch_bounds__(256) void k_branch(
    const float* __restrict__ x, const float* __restrict__ w,
    const float* __restrict__ s, const float* __restrict__ b,
    float* __restrict__ out, int npix) {
    int t = threadIdx.x;
    int f = t & 31;
    int pi = blockIdx.x * 8 + (t >> 5);
    if (pi >= npix) return;
    const float* xr = x + (size_t)pi * CIN;
    float acc = 0.f;
#pragma unroll 4
    for (int c = 0; c < CIN; ++c) acc = fmaf(xr[c], w[c * 32 + f], acc);
    float v = fmaf(acc, s[f], b[f]);
    out[(size_t)pi * 32 + f] = fmaxf(v, 0.f);
}

// ---------- cat builder: a2 (1x1 conv) + bilinear up of a4, a32 -> bf16 ----------
__global__ __launch_bounds__(256) void k_cat(
    const float* __restrict__ feats2, const float* __restrict__ w2,
    const float* __restrict__ s2, const float* __restrict__ b2,
    const float* __restrict__ a4, const float* __restrict__ a32,
    unsigned short* __restrict__ cat) {
    int t = threadIdx.x;
    int f = t & 31;
    int p = blockIdx.x * 8 + (t >> 5);   // 0..65535
    int y = p >> 8, x = p & 255;

    {
        const float* xr = feats2 + (size_t)p * 64;
        float acc = 0.f;
#pragma unroll 4
        for (int c = 0; c < 64; ++c) acc = fmaf(xr[c], w2[c * 32 + f], acc);
        float v = fmaf(acc, s2[f], b2[f]);
        cat[(size_t)p * 96 + f] = f2bf(fmaxf(v, 0.f));
    }
    {
        float sy = fminf(fmaxf(y * 0.5f - 0.25f, 0.f), 127.f);
        float sx = fminf(fmaxf(x * 0.5f - 0.25f, 0.f), 127.f);
        int y0 = (int)sy; float fy = sy - (float)y0; int y1 = min(y0 + 1, 127);
        int x0 = (int)sx; float fx = sx - (float)x0; int x1 = min(x0 + 1, 127);
        float v00 = a4[((size_t)(y0 * 128 + x0)) * 32 + f];
        float v01 = a4[((size_t)(y0 * 128 + x1)) * 32 + f];
        float v10 = a4[((size_t)(y1 * 128 + x0)) * 32 + f];
        float v11 = a4[((size_t)(y1 * 128 + x1)) * 32 + f];
        float vv = (1.f - fy) * ((1.f - fx) * v00 + fx * v01)
                 + fy * ((1.f - fx) * v10 + fx * v11);
        cat[(size_t)p * 96 + 32 + f] = f2bf(vv);
    }
    {
        float sy = fminf(fmaxf((y + 0.5f) * (1.f / 16.f) - 0.5f, 0.f), 15.f);
        float sx = fminf(fmaxf((x + 0.5f) * (1.f / 16.f) - 0.5f, 0.f), 15.f);
        int y0 = (int)sy; float fy = sy - (float)y0; int y1 = min(y0 + 1, 15);
        int x0 = (int)sx; float fx = sx - (float)x0; int x1 = min(x0 + 1, 15);
        float v00 = a32[((size_t)(y0 * 16 + x0)) * 32 + f];
        float v01 = a32[((size_t)(y0 * 16 + x1)) * 32 + f];
        float v10 = a32[((size_t)(y1 * 16 + x0)) * 32 + f];
        float v11 = a32[((size_t)(y1 * 16 + x1)) * 32 + f];
        float vv = (1.f - fy) * ((1.f - fx) * v00 + fx * v01)
                 + fy * ((1.f - fx) * v10 + fx * v11);
        cat[(size_t)p * 96 + 64 + f] = f2bf(vv);
    }
}

// ---------- pack 3x3 fuse weights to MFMA B-fragment order ----------
__global__ __launch_bounds__(256) void k_packf(
    const float* __restrict__ wf, short* __restrict__ wfp) {
    int i = blockIdx.x * 256 + threadIdx.x;   // 0..82943
    if (i >= 82944) return;
    int j = i & 7;
    int l = (i >> 3) & 63;
    int rest = i >> 9;       // 0..161
    int nt = rest % 6;
    int tk = rest / 6;       // 0..26
    int kt = tk % 3, tap = tk / 3;
    int k = kt * 32 + ((l >> 4) << 3) + j;
    int n = nt * 16 + (l & 15);
    wfp[i] = (short)f2bf(wf[((size_t)(tap * 96 + k)) * 96 + n]);
}

// ---------- pack W1 (4 kt) and W0-feat (3 kt) into B-frag order ----------
__global__ __launch_bounds__(256) void k_pack2(
    const float* __restrict__ w0, const float* __restrict__ w1,
    short* __restrict__ w1p, short* __restrict__ w0fp) {
    int i = blockIdx.x * 256 + threadIdx.x;   // 0..28671
    if (i < 16384) {
        int j = i & 7;
        int l = (i >> 3) & 63;
        int nt = (i >> 9) & 7;
        int kt = i >> 12;
        int k = kt * 32 + ((l >> 4) << 3) + j;
        int n = nt * 16 + (l & 15);
        w1p[i] = (short)f2bf(w1[k * 128 + n]);
    } else {
        int i2 = i - 16384;                   // 0..12287
        int j = i2 & 7;
        int l = (i2 >> 3) & 63;
        int nt = (i2 >> 9) & 7;
        int kt = i2 >> 12;                    // 0..2
        int k = kt * 32 + ((l >> 4) << 3) + j;   // 0..95
        int n = nt * 16 + (l & 15);
        w0fp[i2] = (short)f2bf(w0[k * 128 + n]);
    }
}

// ---------- corr[case][d] = ry*W0y[d] + rx*W0x[d] + b0[d], case=(ry2+1)*4+(rx2+1) ----------
__global__ __launch_bounds__(256) void k_corr(
    const float* __restrict__ w0, const float* __restrict__ b0,
    float* __restrict__ corr) {
    int i = blockIdx.x * 256 + threadIdx.x;   // 0..2047
    int d = i & 127, c = i >> 7;
    float ry = (float)(c >> 2) - 1.5f;
    float rx = (float)(c & 3) - 1.5f;
    corr[i] = fmaf(ry, w0[96 * 128 + d], fmaf(rx, w0[97 * 128 + d], b0[d]));
}

// ---------- 3x3 conv (MFMA) + BN + ReLU -> feat (LDS) -> G = feat @ W0f ----------
__global__ __launch_bounds__(256, 4) void k_fuseG(
    const unsigned short* __restrict__ catb, const short* __restrict__ wfp,
    const float* __restrict__ sf, const float* __restrict__ bfb,
    const short* __restrict__ w0fp, unsigned short* __restrict__ G) {
    __shared__ char Xb[100 * 256];
    int t = threadIdx.x;
    int by = (blockIdx.x >> 5) * 8;
    int bx = (blockIdx.x & 31) * 8;

    if (t < 200) {
        int rp = t >> 1, hf = t & 1;
        int gy = by + rp / 10 - 1;
        int gx = bx + rp % 10 - 1;
        bool ok = (gy >= 0 && gy < 256 && gx >= 0 && gx < 256);
        const unsigned short* src = catb + (size_t)(gy * 256 + gx) * 96 + hf * 48;
        int swz = (rp & 7) << 4;
#pragma unroll
        for (int m = 0; m < 6; ++m) {
            short8v v = {0, 0, 0, 0, 0, 0, 0, 0};
            if (ok) v = *(const short8v*)(src + m * 8);
            *(short8v*)(Xb + rp * 256 + (((hf * 6 + m) * 16) ^ swz)) = v;
        }
    }
    __syncthreads();

    int lane = t & 63, wid = t >> 6;
    int wr = wid >> 1, wc = wid & 1;
    int l15 = lane & 15, g = lane >> 4, kb = g * 16;

    float4v acc[2][3];
#pragma unroll
    for (int rb = 0; rb < 2; ++rb)
#pragma unroll
        for (int n = 0; n < 3; ++n)
            acc[rb][n] = (float4v){0.f, 0.f, 0.f, 0.f};

#pragma unroll
    for (int ky = 0; ky < 3; ++ky) {
#pragma unroll
        for (int kx = 0; kx < 3; ++kx) {
#pragma unroll
            for (int kt = 0; kt < 3; ++kt) {
                const short8v* bp = (const short8v*)wfp
                    + (size_t)((((ky * 3 + kx) * 3 + kt) * 6) + wc * 3) * 64 + lane;
                short8v b0 = bp[0], b1 = bp[64], b2 = bp[128];
#pragma unroll
                for (int rb = 0; rb < 2; ++rb) {
                    int R = wr * 32 + rb * 16 + l15;
                    int rp = ((R >> 3) + ky) * 10 + (R & 7) + kx;
                    short8v a = *(short8v*)(Xb + rp * 256
                                 + ((kt * 64 + kb) ^ ((rp & 7) << 4)));
                    acc[rb][0] = __builtin_amdgcn_mfma_f32_16x16x32_bf16(a, b0, acc[rb][0], 0, 0, 0);
                    acc[rb][1] = __builtin_amdgcn_mfma_f32_16x16x32_bf16(a, b1, acc[rb][1], 0, 0, 0);
                    acc[rb][2] = __builtin_amdgcn_mfma_f32_16x16x32_bf16(a, b2, acc[rb][2], 0, 0, 0);
                }
            }
        }
    }
    __syncthreads();   // conv LDS reads done; Xb reusable

    // feat (bf16, BN+ReLU applied) -> Xb as [64 rows][96 ch], pitch 256, swizzled
#pragma unroll
    for (int rb = 0; rb < 2; ++rb) {
#pragma unroll
        for (int n = 0; n < 3; ++n) {
            int ch = (wc * 3 + n) * 16 + l15;
            float sc = sf[ch], bi = bfb[ch];
#pragma unroll
            for (int j = 0; j < 4; ++j) {
                int R = wr * 32 + rb * 16 + g * 4 + j;
                *(short*)(Xb + R * 256 + ((ch * 2) ^ ((R & 7) << 4))) =
                    (short)f2bf(fmaxf(fmaf(acc[rb][n][j], sc, bi), 0.f));
            }
        }
    }
    __syncthreads();

    // G-stage: 64 rows x 128 cols, K=96. Wave wid owns cols [32*wid, 32*wid+32).
    float4v a2[4][2];
#pragma unroll
    for (int r = 0; r < 4; ++r)
#pragma unroll
        for (int n = 0; n < 2; ++n)
            a2[r][n] = (float4v){0.f, 0.f, 0.f, 0.f};

#pragma unroll
    for (int kt = 0; kt < 3; ++kt) {
        const short8v* bp = (const short8v*)w0fp + (kt * 8 + wid * 2) * 64 + lane;
        short8v b0 = bp[0], b1 = bp[64];
#pragma unroll
        for (int r = 0; r < 4; ++r) {
            int row = r * 16 + l15;
            short8v a = *(short8v*)(Xb + row * 256 + ((kt * 64 + kb) ^ ((row & 7) << 4)));
            a2[r][0] = __builtin_amdgcn_mfma_f32_16x16x32_bf16(a, b0, a2[r][0], 0, 0, 0);
            a2[r][1] = __builtin_amdgcn_mfma_f32_16x16x32_bf16(a, b1, a2[r][1], 0, 0, 0);
        }
    }

#pragma unroll
    for (int r = 0; r < 4; ++r) {
#pragma unroll
        for (int n = 0; n < 2; ++n) {
            int colg = (wid * 2 + n) * 16 + l15;
#pragma unroll
            for (int j = 0; j < 4; ++j) {
                int R = r * 16 + g * 4 + j;
                int pix = (by + (R >> 3)) * 256 + bx + (R & 7);
                G[(size_t)pix * 128 + colg] = f2bf(a2[r][n][j]);
            }
        }
    }
}

// ---------- fused LIIF query: in-register A-frag build + layer1 MFMA ----------
// 8192 blocks (XCD-swizzled), 4 waves, 32 px = 128 rows. M-split: wave owns
// 32 rows x all 128 cols. No H LDS round trip; LDS = 512B preds only.
// Exact int coord path: iy = clamp((qy+s)>>1,0,255); ry = qy-2*iy-0.5
// (proved identical to the f32 shift/clip/rint reference path).
__global__ __launch_bounds__(256) void k_mlp6(
    const unsigned short* __restrict__ G,
    const float* __restrict__ corr,
    const short* __restrict__ w1p, const float* __restrict__ b1g,
    const float* __restrict__ w2g, const float* __restrict__ b2g,
    float* __restrict__ out) {
    __shared__ float preds[128];
    int t = threadIdx.x;
    int swzb = ((blockIdx.x & 7) << 10) + (blockIdx.x >> 3);   // bijective XCD swizzle
    int pixbase = swzb * 32;
    int lane = t & 63, wid = t >> 6;
    int l15 = lane & 15, g = lane >> 4;

    // ---- build layer-1 A-fragments in registers ----
    short8v afrag[2][4];
#pragma unroll
    for (int rt = 0; rt < 2; ++rt) {
        int row = wid * 32 + rt * 16 + l15;
        int p = pixbase + (row >> 2);
        int br = row & 3;
        int qy = p >> 9, qx = p & 511;
        int iy = min(max((qy + ((br & 2) ? 1 : -1)) >> 1, 0), 255);
        int ix = min(max((qx + ((br & 1) ? 1 : -1)) >> 1, 0), 255);
        int ry2 = qy - 2 * iy, rx2 = qx - 2 * ix;   // in {-1,0,1,2}
        const unsigned short* gp = G + ((size_t)(iy * 256 + ix)) * 128 + g * 8;
        const float* cp = corr + ((ry2 + 1) * 4 + (rx2 + 1)) * 128 + g * 8;
#pragma unroll
        for (int kt = 0; kt < 4; ++kt) {
            short8v gv = *(const short8v*)(gp + kt * 32);
            float4 c0 = *(const float4*)(cp + kt * 32);
            float4 c1 = *(const float4*)(cp + kt * 32 + 4);
            uint4v u;
            u[0] = cvt_pk_bf16(fmaxf(bf2f((unsigned short)gv[0]) + c0.x, 0.f),
                               fmaxf(bf2f((unsigned short)gv[1]) + c0.y, 0.f));
            u[1] = cvt_pk_bf16(fmaxf(bf2f((unsigned short)gv[2]) + c0.z, 0.f),
                               fmaxf(bf2f((unsigned short)gv[3]) + c0.w, 0.f));
            u[2] = cvt_pk_bf16(fmaxf(bf2f((unsigned short)gv[4]) + c1.x, 0.f),
                               fmaxf(bf2f((unsigned short)gv[5]) + c1.y, 0.f));
            u[3] = cvt_pk_bf16(fmaxf(bf2f((unsigned short)gv[6]) + c1.z, 0.f),
                               fmaxf(bf2f((unsigned short)gv[7]) + c1.w, 0.f));
            afrag[rt][kt] = __builtin_bit_cast(short8v, u);
        }
    }

    // ---- layer 1: 32 rows (this wave) x 128 cols ----
    float4v acc[2][8];
#pragma unroll
    for (int rt = 0; rt < 2; ++rt)
#pragma unroll
        for (int nt = 0; nt < 8; ++nt)
            acc[rt][nt] = (float4v){0.f, 0.f, 0.f, 0.f};

#pragma unroll
    for (int kt = 0; kt < 4; ++kt) {
        const short8v* bp = (const short8v*)w1p + kt * 512 + lane;
#pragma unroll
        for (int nt = 0; nt < 8; ++nt) {
            short8v b = bp[nt * 64];
            acc[0][nt] = __builtin_amdgcn_mfma_f32_16x16x32_bf16(afrag[0][kt], b, acc[0][nt], 0, 0, 0);
            acc[1][nt] = __builtin_amdgcn_mfma_f32_16x16x32_bf16(afrag[1][kt], b, acc[1][nt], 0, 0, 0);
        }
    }

    // ---- fused layer 2 + 16-lane reduce (full dot within wave) ----
    float b1v[8], w2v[8];
#pragma unroll
    for (int nt = 0; nt < 8; ++nt) {
        b1v[nt] = b1g[nt * 16 + l15];
        w2v[nt] = w2g[nt * 16 + l15];
    }
    float part[2][4];
#pragma unroll
    for (int rt = 0; rt < 2; ++rt)
#pragma unroll
        for (int j = 0; j < 4; ++j) part[rt][j] = 0.f;
#pragma unroll
    for (int rt = 0; rt < 2; ++rt)
#pragma unroll
        for (int nt = 0; nt < 8; ++nt)
#pragma unroll
            for (int j = 0; j < 4; ++j)
                part[rt][j] += fmaxf(acc[rt][nt][j] + b1v[nt], 0.f) * w2v[nt];
#pragma unroll
    for (int off = 8; off >= 1; off >>= 1)
#pragma unroll
        for (int rt = 0; rt < 2; ++rt)
#pragma unroll
            for (int j = 0; j < 4; ++j)
                part[rt][j] += __shfl_xor(part[rt][j], off);

    if (l15 == 0) {
#pragma unroll
        for (int rt = 0; rt < 2; ++rt)
#pragma unroll
            for (int j = 0; j < 4; ++j)
                preds[wid * 32 + rt * 16 + g * 4 + j] = part[rt][j];
    }
    __syncthreads();

    // ---- epilogue: areas via exact int path + local ensemble ----
    if (t < 32) {
        float bb = b2g[0];
        int p = pixbase + t;
        int qy = p >> 9, qx = p & 511;
        float pr[4], ar[4];
#pragma unroll
        for (int br = 0; br < 4; ++br) {
            int iy = min(max((qy + ((br & 2) ? 1 : -1)) >> 1, 0), 255);
            int ix = min(max((qx + ((br & 1) ? 1 : -1)) >> 1, 0), 255);
            float ry = (float)(qy - 2 * iy) - 0.5f;
            float rx = (float)(qx - 2 * ix) - 0.5f;
            ar[br] = fabsf(ry * rx) + 1e-9f;
            pr[br] = preds[t * 4 + br] + bb;
        }
        out[pixbase + t] =
            (pr[0] * ar[3] + pr[1] * ar[2] + pr[2] * ar[1] + pr[3] * ar[0])
            / (ar[0] + ar[1] + ar[2] + ar[3]);
    }
}

// ---------- host launcher ----------
extern "C" void kernel_launch(void* const* d_in, const int* in_sizes, int n_in,
                              void* d_out, int out_size, void* d_ws, size_t ws_size,
                              hipStream_t stream) {
    const float* feats2 = (const float*)d_in[0];
    const float* feats4 = (const float*)d_in[1];
    const float* feats32 = (const float*)d_in[2];
    const float* w2 = (const float*)d_in[4];
    const float* s2 = (const float*)d_in[5];
    const float* b2 = (const float*)d_in[6];
    const float* w4 = (const float*)d_in[7];
    const float* s4 = (const float*)d_in[8];
    const float* b4 = (const float*)d_in[9];
    const float* w32 = (const float*)d_in[10];
    const float* s32 = (const float*)d_in[11];
    const float* b32 = (const float*)d_in[12];
    const float* wf = (const float*)d_in[13];
    const float* sf = (const float*)d_in[14];
    const float* bf = (const float*)d_in[15];
    const float* mw0 = (const float*)d_in[16];
    const float* mb0 = (const float*)d_in[17];
    const float* mw1 = (const float*)d_in[18];
    const float* mb1 = (const float*)d_in[19];
    const float* mw2 = (const float*)d_in[20];
    const float* mb2 = (const float*)d_in[21];

    float* a4buf = (float*)d_ws;                          // 128*128*32 f32
    float* a32buf = a4buf + 524288;                       // 16*16*32 f32
    unsigned short* catb16 = (unsigned short*)(a32buf + 8192);   // 65536*96 bf16
    unsigned short* Gbuf = catb16 + 6291456;                     // 65536*128 bf16
    short* w1p = (short*)(Gbuf + 8388608);                // 16384 bf16
    short* w0fp = w1p + 16384;                            // 12288 bf16
    short* wfp = w0fp + 12288;                            // 82944 bf16
    float* corrbuf = (float*)(wfp + 82944);               // 16*128 f32

    k_pack2<<<112, 256, 0, stream>>>(mw0, mw1, w1p, w0fp);
    k_packf<<<324, 256, 0, stream>>>(wf, wfp);
    k_corr<<<8, 256, 0, stream>>>(mw0, mb0, corrbuf);
    k_branch<128><<<2048, 256, 0, stream>>>(feats4, w4, s4, b4, a4buf, 16384);
    k_branch<256><<<32, 256, 0, stream>>>(feats32, w32, s32, b32, a32buf, 256);
    k_cat<<<8192, 256, 0, stream>>>(feats2, w2, s2, b2, a4buf, a32buf, catb16);
    k_fuseG<<<1024, 256, 0, stream>>>(catb16, wfp, sf, bf, w0fp, Gbuf);
    k_mlp6<<<8192, 256, 0, stream>>>(Gbuf, corrbuf, w1p, mb1, mw2, mb2,
                                     (float*)d_out);
}

// Round 8
// 202.223 us; speedup vs baseline: 1.1761x; 1.1761x over previous
//
#include <hip/hip_runtime.h>
#include <hip/hip_bf16.h>

typedef __attribute__((ext_vector_type(8))) short short8v;
typedef __attribute__((ext_vector_type(4))) float float4v;
typedef __attribute__((ext_vector_type(4))) unsigned uint4v;

__device__ __forceinline__ unsigned short f2bf(float x) {
    unsigned u = __float_as_uint(x);
    unsigned r = (u + 0x7fffu + ((u >> 16) & 1u)) >> 16;
    return (unsigned short)r;
}
__device__ __forceinline__ float bf2f(unsigned short u) {
    return __uint_as_float((unsigned)u << 16);
}
__device__ __forceinline__ unsigned cvt_pk_bf16(float lo, float hi) {
    unsigned r;
    asm("v_cvt_pk_bf16_f32 %0, %1, %2" : "=v"(r) : "v"(lo), "v"(hi));
    return r;
}

// ---------- branch 1x1 conv + BN + ReLU (a4: CIN=128, a32: CIN=256) ----------
template<int CIN>
__global__ __launch_bounds__(256) void k_branch(
    const float* __restrict__ x, const float* __restrict__ w,
    const float* __restrict__ s, const float* __restrict__ b,
    float* __restrict__ out, int npix) {
    int t = threadIdx.x;
    int f = t & 31;
    int pi = blockIdx.x * 8 + (t >> 5);
    if (pi >= npix) return;
    const float* xr = x + (size_t)pi * CIN;
    float acc = 0.f;
#pragma unroll 4
    for (int c = 0; c < CIN; ++c) acc = fmaf(xr[c], w[c * 32 + f], acc);
    float v = fmaf(acc, s[f], b[f]);
    out[(size_t)pi * 32 + f] = fmaxf(v, 0.f);
}

// ---------- cat builder: a2 (1x1 conv) + bilinear up of a4, a32 -> bf16 ----------
__global__ __launch_bounds__(256) void k_cat(
    const float* __restrict__ feats2, const float* __restrict__ w2,
    const float* __restrict__ s2, const float* __restrict__ b2,
    const float* __restrict__ a4, const float* __restrict__ a32,
    unsigned short* __restrict__ cat) {
    int t = threadIdx.x;
    int f = t & 31;
    int p = blockIdx.x * 8 + (t >> 5);   // 0..65535
    int y = p >> 8, x = p & 255;

    {
        const float* xr = feats2 + (size_t)p * 64;
        float acc = 0.f;
#pragma unroll 4
        for (int c = 0; c < 64; ++c) acc = fmaf(xr[c], w2[c * 32 + f], acc);
        float v = fmaf(acc, s2[f], b2[f]);
        cat[(size_t)p * 96 + f] = f2bf(fmaxf(v, 0.f));
    }
    {
        float sy = fminf(fmaxf(y * 0.5f - 0.25f, 0.f), 127.f);
        float sx = fminf(fmaxf(x * 0.5f - 0.25f, 0.f), 127.f);
        int y0 = (int)sy; float fy = sy - (float)y0; int y1 = min(y0 + 1, 127);
        int x0 = (int)sx; float fx = sx - (float)x0; int x1 = min(x0 + 1, 127);
        float v00 = a4[((size_t)(y0 * 128 + x0)) * 32 + f];
        float v01 = a4[((size_t)(y0 * 128 + x1)) * 32 + f];
        float v10 = a4[((size_t)(y1 * 128 + x0)) * 32 + f];
        float v11 = a4[((size_t)(y1 * 128 + x1)) * 32 + f];
        float vv = (1.f - fy) * ((1.f - fx) * v00 + fx * v01)
                 + fy * ((1.f - fx) * v10 + fx * v11);
        cat[(size_t)p * 96 + 32 + f] = f2bf(vv);
    }
    {
        float sy = fminf(fmaxf((y + 0.5f) * (1.f / 16.f) - 0.5f, 0.f), 15.f);
        float sx = fminf(fmaxf((x + 0.5f) * (1.f / 16.f) - 0.5f, 0.f), 15.f);
        int y0 = (int)sy; float fy = sy - (float)y0; int y1 = min(y0 + 1, 15);
        int x0 = (int)sx; float fx = sx - (float)x0; int x1 = min(x0 + 1, 15);
        float v00 = a32[((size_t)(y0 * 16 + x0)) * 32 + f];
        float v01 = a32[((size_t)(y0 * 16 + x1)) * 32 + f];
        float v10 = a32[((size_t)(y1 * 16 + x0)) * 32 + f];
        float v11 = a32[((size_t)(y1 * 16 + x1)) * 32 + f];
        float vv = (1.f - fy) * ((1.f - fx) * v00 + fx * v01)
                 + fy * ((1.f - fx) * v10 + fx * v11);
        cat[(size_t)p * 96 + 64 + f] = f2bf(vv);
    }
}

// ---------- pack 3x3 fuse weights to MFMA B-fragment order ----------
__global__ __launch_bounds__(256) void k_packf(
    const float* __restrict__ wf, short* __restrict__ wfp) {
    int i = blockIdx.x * 256 + threadIdx.x;   // 0..82943
    if (i >= 82944) return;
    int j = i & 7;
    int l = (i >> 3) & 63;
    int rest = i >> 9;       // 0..161
    int nt = rest % 6;
    int tk = rest / 6;       // 0..26
    int kt = tk % 3, tap = tk / 3;
    int k = kt * 32 + ((l >> 4) << 3) + j;
    int n = nt * 16 + (l & 15);
    wfp[i] = (short)f2bf(wf[((size_t)(tap * 96 + k)) * 96 + n]);
}

// ---------- pack W1 (4 kt) and W0-feat (3 kt) into B-frag order ----------
__global__ __launch_bounds__(256) void k_pack2(
    const float* __restrict__ w0, const float* __restrict__ w1,
    short* __restrict__ w1p, short* __restrict__ w0fp) {
    int i = blockIdx.x * 256 + threadIdx.x;   // 0..28671
    if (i < 16384) {
        int j = i & 7;
        int l = (i >> 3) & 63;
        int nt = (i >> 9) & 7;
        int kt = i >> 12;
        int k = kt * 32 + ((l >> 4) << 3) + j;
        int n = nt * 16 + (l & 15);
        w1p[i] = (short)f2bf(w1[k * 128 + n]);
    } else {
        int i2 = i - 16384;                   // 0..12287
        int j = i2 & 7;
        int l = (i2 >> 3) & 63;
        int nt = (i2 >> 9) & 7;
        int kt = i2 >> 12;                    // 0..2
        int k = kt * 32 + ((l >> 4) << 3) + j;   // 0..95
        int n = nt * 16 + (l & 15);
        w0fp[i2] = (short)f2bf(w0[k * 128 + n]);
    }
}

// ---------- corr[case][d] = ry*W0y[d] + rx*W0x[d] + b0[d], case=(ry2+1)*4+(rx2+1) ----------
__global__ __launch_bounds__(256) void k_corr(
    const float* __restrict__ w0, const float* __restrict__ b0,
    float* __restrict__ corr) {
    int i = blockIdx.x * 256 + threadIdx.x;   // 0..2047
    int d = i & 127, c = i >> 7;
    float ry = (float)(c >> 2) - 1.5f;
    float rx = (float)(c & 3) - 1.5f;
    corr[i] = fmaf(ry, w0[96 * 128 + d], fmaf(rx, w0[97 * 128 + d], b0[d]));
}

// ---------- 3x3 conv (MFMA) + BN + ReLU -> feat (LDS) -> G = feat @ W0f ----------
__global__ __launch_bounds__(256, 4) void k_fuseG(
    const unsigned short* __restrict__ catb, const short* __restrict__ wfp,
    const float* __restrict__ sf, const float* __restrict__ bfb,
    const short* __restrict__ w0fp, unsigned short* __restrict__ G) {
    __shared__ char Xb[100 * 256];
    int t = threadIdx.x;
    int by = (blockIdx.x >> 5) * 8;
    int bx = (blockIdx.x & 31) * 8;

    if (t < 200) {
        int rp = t >> 1, hf = t & 1;
        int gy = by + rp / 10 - 1;
        int gx = bx + rp % 10 - 1;
        bool ok = (gy >= 0 && gy < 256 && gx >= 0 && gx < 256);
        const unsigned short* src = catb + (size_t)(gy * 256 + gx) * 96 + hf * 48;
        int swz = (rp & 7) << 4;
#pragma unroll
        for (int m = 0; m < 6; ++m) {
            short8v v = {0, 0, 0, 0, 0, 0, 0, 0};
            if (ok) v = *(const short8v*)(src + m * 8);
            *(short8v*)(Xb + rp * 256 + (((hf * 6 + m) * 16) ^ swz)) = v;
        }
    }
    __syncthreads();

    int lane = t & 63, wid = t >> 6;
    int wr = wid >> 1, wc = wid & 1;
    int l15 = lane & 15, g = lane >> 4, kb = g * 16;

    float4v acc[2][3];
#pragma unroll
    for (int rb = 0; rb < 2; ++rb)
#pragma unroll
        for (int n = 0; n < 3; ++n)
            acc[rb][n] = (float4v){0.f, 0.f, 0.f, 0.f};

#pragma unroll
    for (int ky = 0; ky < 3; ++ky) {
#pragma unroll
        for (int kx = 0; kx < 3; ++kx) {
#pragma unroll
            for (int kt = 0; kt < 3; ++kt) {
                const short8v* bp = (const short8v*)wfp
                    + (size_t)((((ky * 3 + kx) * 3 + kt) * 6) + wc * 3) * 64 + lane;
                short8v b0 = bp[0], b1 = bp[64], b2 = bp[128];
#pragma unroll
                for (int rb = 0; rb < 2; ++rb) {
                    int R = wr * 32 + rb * 16 + l15;
                    int rp = ((R >> 3) + ky) * 10 + (R & 7) + kx;
                    short8v a = *(short8v*)(Xb + rp * 256
                                 + ((kt * 64 + kb) ^ ((rp & 7) << 4)));
                    acc[rb][0] = __builtin_amdgcn_mfma_f32_16x16x32_bf16(a, b0, acc[rb][0], 0, 0, 0);
                    acc[rb][1] = __builtin_amdgcn_mfma_f32_16x16x32_bf16(a, b1, acc[rb][1], 0, 0, 0);
                    acc[rb][2] = __builtin_amdgcn_mfma_f32_16x16x32_bf16(a, b2, acc[rb][2], 0, 0, 0);
                }
            }
        }
    }
    __syncthreads();   // conv LDS reads done; Xb reusable

    // feat (bf16, BN+ReLU applied) -> Xb as [64 rows][96 ch], pitch 256, swizzled
#pragma unroll
    for (int rb = 0; rb < 2; ++rb) {
#pragma unroll
        for (int n = 0; n < 3; ++n) {
            int ch = (wc * 3 + n) * 16 + l15;
            float sc = sf[ch], bi = bfb[ch];
#pragma unroll
            for (int j = 0; j < 4; ++j) {
                int R = wr * 32 + rb * 16 + g * 4 + j;
                *(short*)(Xb + R * 256 + ((ch * 2) ^ ((R & 7) << 4))) =
                    (short)f2bf(fmaxf(fmaf(acc[rb][n][j], sc, bi), 0.f));
            }
        }
    }
    __syncthreads();

    // G-stage: 64 rows x 128 cols, K=96. Wave wid owns cols [32*wid, 32*wid+32).
    float4v a2[4][2];
#pragma unroll
    for (int r = 0; r < 4; ++r)
#pragma unroll
        for (int n = 0; n < 2; ++n)
            a2[r][n] = (float4v){0.f, 0.f, 0.f, 0.f};

#pragma unroll
    for (int kt = 0; kt < 3; ++kt) {
        const short8v* bp = (const short8v*)w0fp + (kt * 8 + wid * 2) * 64 + lane;
        short8v b0 = bp[0], b1 = bp[64];
#pragma unroll
        for (int r = 0; r < 4; ++r) {
            int row = r * 16 + l15;
            short8v a = *(short8v*)(Xb + row * 256 + ((kt * 64 + kb) ^ ((row & 7) << 4)));
            a2[r][0] = __builtin_amdgcn_mfma_f32_16x16x32_bf16(a, b0, a2[r][0], 0, 0, 0);
            a2[r][1] = __builtin_amdgcn_mfma_f32_16x16x32_bf16(a, b1, a2[r][1], 0, 0, 0);
        }
    }

#pragma unroll
    for (int r = 0; r < 4; ++r) {
#pragma unroll
        for (int n = 0; n < 2; ++n) {
            int colg = (wid * 2 + n) * 16 + l15;
#pragma unroll
            for (int j = 0; j < 4; ++j) {
                int R = r * 16 + g * 4 + j;
                int pix = (by + (R >> 3)) * 256 + bx + (R & 7);
                G[(size_t)pix * 128 + colg] = f2bf(a2[r][n][j]);
            }
        }
    }
}

// ---------- fused LIIF query: W1 staged in LDS, in-register A-frags, 2 sub-tiles ----------
// 4096 blocks (XCD-swizzled), 4 waves, 64 px = 2 sub-tiles of 32 px (128 rows).
// M-split: wave owns 32 rows x all 128 cols. B-frags = conflict-free ds_read_b128.
// Sub-tile 1's G rows prefetched to registers during sub-tile 0's tail (T14).
__global__ __launch_bounds__(256) void k_mlp7(
    const unsigned short* __restrict__ G,
    const float* __restrict__ corr,
    const short* __restrict__ w1p, const float* __restrict__ b1g,
    const float* __restrict__ w2g, const float* __restrict__ b2g,
    float* __restrict__ out) {
    __shared__ short8v Bs[2048];       // 32KB packed W1
    __shared__ float preds[2][128];
    int t = threadIdx.x;
    int swzb = ((blockIdx.x & 7) << 9) + (blockIdx.x >> 3);   // bijective XCD swizzle
    int pixbase = swzb * 64;
    int lane = t & 63, wid = t >> 6;
    int l15 = lane & 15, g = lane >> 4;

    // ---- stage W1 into LDS (coalesced, once per block) ----
    {
        const short8v* wp = (const short8v*)w1p;
#pragma unroll
        for (int i = 0; i < 8; ++i)
            Bs[t + i * 256] = wp[t + i * 256];
    }

    float b1v[8], w2v[8];
#pragma unroll
    for (int nt = 0; nt < 8; ++nt) {
        b1v[nt] = b1g[nt * 16 + l15];
        w2v[nt] = w2g[nt * 16 + l15];
    }
    float bb = b2g[0];

    // ---- gather + build A-frags for sub-tile 0 ----
    short8v afrag[2][4];
#pragma unroll
    for (int rt = 0; rt < 2; ++rt) {
        int row = wid * 32 + rt * 16 + l15;
        int p = pixbase + (row >> 2);
        int br = row & 3;
        int qy = p >> 9, qx = p & 511;
        int iy = min(max((qy + ((br & 2) ? 1 : -1)) >> 1, 0), 255);
        int ix = min(max((qx + ((br & 1) ? 1 : -1)) >> 1, 0), 255);
        int ry2 = qy - 2 * iy, rx2 = qx - 2 * ix;
        const unsigned short* gp = G + ((size_t)(iy * 256 + ix)) * 128 + g * 8;
        const float* cp = corr + ((ry2 + 1) * 4 + (rx2 + 1)) * 128 + g * 8;
#pragma unroll
        for (int kt = 0; kt < 4; ++kt) {
            short8v gv = *(const short8v*)(gp + kt * 32);
            float4 c0 = *(const float4*)(cp + kt * 32);
            float4 c1 = *(const float4*)(cp + kt * 32 + 4);
            uint4v u;
            u[0] = cvt_pk_bf16(fmaxf(bf2f((unsigned short)gv[0]) + c0.x, 0.f),
                               fmaxf(bf2f((unsigned short)gv[1]) + c0.y, 0.f));
            u[1] = cvt_pk_bf16(fmaxf(bf2f((unsigned short)gv[2]) + c0.z, 0.f),
                               fmaxf(bf2f((unsigned short)gv[3]) + c0.w, 0.f));
            u[2] = cvt_pk_bf16(fmaxf(bf2f((unsigned short)gv[4]) + c1.x, 0.f),
                               fmaxf(bf2f((unsigned short)gv[5]) + c1.y, 0.f));
            u[3] = cvt_pk_bf16(fmaxf(bf2f((unsigned short)gv[6]) + c1.z, 0.f),
                               fmaxf(bf2f((unsigned short)gv[7]) + c1.w, 0.f));
            afrag[rt][kt] = __builtin_bit_cast(short8v, u);
        }
    }
    __syncthreads();   // Bs staged

    // ---- layer 1 MFMA, sub-tile 0 (B from LDS) ----
    float4v acc[2][8];
#pragma unroll
    for (int rt = 0; rt < 2; ++rt)
#pragma unroll
        for (int nt = 0; nt < 8; ++nt)
            acc[rt][nt] = (float4v){0.f, 0.f, 0.f, 0.f};
#pragma unroll
    for (int kt = 0; kt < 4; ++kt) {
#pragma unroll
        for (int nt = 0; nt < 8; ++nt) {
            short8v b = Bs[(kt * 8 + nt) * 64 + lane];
            acc[0][nt] = __builtin_amdgcn_mfma_f32_16x16x32_bf16(afrag[0][kt], b, acc[0][nt], 0, 0, 0);
            acc[1][nt] = __builtin_amdgcn_mfma_f32_16x16x32_bf16(afrag[1][kt], b, acc[1][nt], 0, 0, 0);
        }
    }

    // ---- prefetch sub-tile 1's G rows (issue early, consume late) ----
    short8v gv1[2][4];
    const float* cp1[2];
#pragma unroll
    for (int rt = 0; rt < 2; ++rt) {
        int row = wid * 32 + rt * 16 + l15;
        int p = pixbase + 32 + (row >> 2);
        int br = row & 3;
        int qy = p >> 9, qx = p & 511;
        int iy = min(max((qy + ((br & 2) ? 1 : -1)) >> 1, 0), 255);
        int ix = min(max((qx + ((br & 1) ? 1 : -1)) >> 1, 0), 255);
        int ry2 = qy - 2 * iy, rx2 = qx - 2 * ix;
        const unsigned short* gp = G + ((size_t)(iy * 256 + ix)) * 128 + g * 8;
        cp1[rt] = corr + ((ry2 + 1) * 4 + (rx2 + 1)) * 128 + g * 8;
#pragma unroll
        for (int kt = 0; kt < 4; ++kt)
            gv1[rt][kt] = *(const short8v*)(gp + kt * 32);
    }

    // ---- layer 2 + reduce, sub-tile 0 ----
    {
        float part[2][4];
#pragma unroll
        for (int rt = 0; rt < 2; ++rt)
#pragma unroll
            for (int j = 0; j < 4; ++j) part[rt][j] = 0.f;
#pragma unroll
        for (int rt = 0; rt < 2; ++rt)
#pragma unroll
            for (int nt = 0; nt < 8; ++nt)
#pragma unroll
                for (int j = 0; j < 4; ++j)
                    part[rt][j] += fmaxf(acc[rt][nt][j] + b1v[nt], 0.f) * w2v[nt];
#pragma unroll
        for (int off = 8; off >= 1; off >>= 1)
#pragma unroll
            for (int rt = 0; rt < 2; ++rt)
#pragma unroll
                for (int j = 0; j < 4; ++j)
                    part[rt][j] += __shfl_xor(part[rt][j], off);
        if (l15 == 0) {
#pragma unroll
            for (int rt = 0; rt < 2; ++rt)
#pragma unroll
                for (int j = 0; j < 4; ++j)
                    preds[0][wid * 32 + rt * 16 + g * 4 + j] = part[rt][j];
        }
    }
    __syncthreads();

    // ---- epilogue sub-tile 0 ----
    if (t < 32) {
        int p = pixbase + t;
        int qy = p >> 9, qx = p & 511;
        float pr[4], ar[4];
#pragma unroll
        for (int br = 0; br < 4; ++br) {
            int iy = min(max((qy + ((br & 2) ? 1 : -1)) >> 1, 0), 255);
            int ix = min(max((qx + ((br & 1) ? 1 : -1)) >> 1, 0), 255);
            float ry = (float)(qy - 2 * iy) - 0.5f;
            float rx = (float)(qx - 2 * ix) - 0.5f;
            ar[br] = fabsf(ry * rx) + 1e-9f;
            pr[br] = preds[0][t * 4 + br] + bb;
        }
        out[p] = (pr[0] * ar[3] + pr[1] * ar[2] + pr[2] * ar[1] + pr[3] * ar[0])
               / (ar[0] + ar[1] + ar[2] + ar[3]);
    }

    // ---- build A-frags sub-tile 1 from prefetched gv1 ----
#pragma unroll
    for (int rt = 0; rt < 2; ++rt) {
#pragma unroll
        for (int kt = 0; kt < 4; ++kt) {
            short8v gv = gv1[rt][kt];
            float4 c0 = *(const float4*)(cp1[rt] + kt * 32);
            float4 c1 = *(const float4*)(cp1[rt] + kt * 32 + 4);
            uint4v u;
            u[0] = cvt_pk_bf16(fmaxf(bf2f((unsigned short)gv[0]) + c0.x, 0.f),
                               fmaxf(bf2f((unsigned short)gv[1]) + c0.y, 0.f));
            u[1] = cvt_pk_bf16(fmaxf(bf2f((unsigned short)gv[2]) + c0.z, 0.f),
                               fmaxf(bf2f((unsigned short)gv[3]) + c0.w, 0.f));
            u[2] = cvt_pk_bf16(fmaxf(bf2f((unsigned short)gv[4]) + c1.x, 0.f),
                               fmaxf(bf2f((unsigned short)gv[5]) + c1.y, 0.f));
            u[3] = cvt_pk_bf16(fmaxf(bf2f((unsigned short)gv[6]) + c1.z, 0.f),
                               fmaxf(bf2f((unsigned short)gv[7]) + c1.w, 0.f));
            afrag[rt][kt] = __builtin_bit_cast(short8v, u);
        }
    }

    // ---- layer 1 MFMA, sub-tile 1 ----
#pragma unroll
    for (int rt = 0; rt < 2; ++rt)
#pragma unroll
        for (int nt = 0; nt < 8; ++nt)
            acc[rt][nt] = (float4v){0.f, 0.f, 0.f, 0.f};
#pragma unroll
    for (int kt = 0; kt < 4; ++kt) {
#pragma unroll
        for (int nt = 0; nt < 8; ++nt) {
            short8v b = Bs[(kt * 8 + nt) * 64 + lane];
            acc[0][nt] = __builtin_amdgcn_mfma_f32_16x16x32_bf16(afrag[0][kt], b, acc[0][nt], 0, 0, 0);
            acc[1][nt] = __builtin_amdgcn_mfma_f32_16x16x32_bf16(afrag[1][kt], b, acc[1][nt], 0, 0, 0);
        }
    }

    // ---- layer 2 + reduce, sub-tile 1 ----
    {
        float part[2][4];
#pragma unroll
        for (int rt = 0; rt < 2; ++rt)
#pragma unroll
            for (int j = 0; j < 4; ++j) part[rt][j] = 0.f;
#pragma unroll
        for (int rt = 0; rt < 2; ++rt)
#pragma unroll
            for (int nt = 0; nt < 8; ++nt)
#pragma unroll
                for (int j = 0; j < 4; ++j)
                    part[rt][j] += fmaxf(acc[rt][nt][j] + b1v[nt], 0.f) * w2v[nt];
#pragma unroll
        for (int off = 8; off >= 1; off >>= 1)
#pragma unroll
            for (int rt = 0; rt < 2; ++rt)
#pragma unroll
                for (int j = 0; j < 4; ++j)
                    part[rt][j] += __shfl_xor(part[rt][j], off);
        if (l15 == 0) {
#pragma unroll
            for (int rt = 0; rt < 2; ++rt)
#pragma unroll
                for (int j = 0; j < 4; ++j)
                    preds[1][wid * 32 + rt * 16 + g * 4 + j] = part[rt][j];
        }
    }
    __syncthreads();

    // ---- epilogue sub-tile 1 ----
    if (t < 32) {
        int p = pixbase + 32 + t;
        int qy = p >> 9, qx = p & 511;
        float pr[4], ar[4];
#pragma unroll
        for (int br = 0; br < 4; ++br) {
            int iy = min(max((qy + ((br & 2) ? 1 : -1)) >> 1, 0), 255);
            int ix = min(max((qx + ((br & 1) ? 1 : -1)) >> 1, 0), 255);
            float ry = (float)(qy - 2 * iy) - 0.5f;
            float rx = (float)(qx - 2 * ix) - 0.5f;
            ar[br] = fabsf(ry * rx) + 1e-9f;
            pr[br] = preds[1][t * 4 + br] + bb;
        }
        out[p] = (pr[0] * ar[3] + pr[1] * ar[2] + pr[2] * ar[1] + pr[3] * ar[0])
               / (ar[0] + ar[1] + ar[2] + ar[3]);
    }
}

// ---------- host launcher ----------
extern "C" void kernel_launch(void* const* d_in, const int* in_sizes, int n_in,
                              void* d_out, int out_size, void* d_ws, size_t ws_size,
                              hipStream_t stream) {
    const float* feats2 = (const float*)d_in[0];
    const float* feats4 = (const float*)d_in[1];
    const float* feats32 = (const float*)d_in[2];
    const float* w2 = (const float*)d_in[4];
    const float* s2 = (const float*)d_in[5];
    const float* b2 = (const float*)d_in[6];
    const float* w4 = (const float*)d_in[7];
    const float* s4 = (const float*)d_in[8];
    const float* b4 = (const float*)d_in[9];
    const float* w32 = (const float*)d_in[10];
    const float* s32 = (const float*)d_in[11];
    const float* b32 = (const float*)d_in[12];
    const float* wf = (const float*)d_in[13];
    const float* sf = (const float*)d_in[14];
    const float* bf = (const float*)d_in[15];
    const float* mw0 = (const float*)d_in[16];
    const float* mb0 = (const float*)d_in[17];
    const float* mw1 = (const float*)d_in[18];
    const float* mb1 = (const float*)d_in[19];
    const float* mw2 = (const float*)d_in[20];
    const float* mb2 = (const float*)d_in[21];

    float* a4buf = (float*)d_ws;                          // 128*128*32 f32
    float* a32buf = a4buf + 524288;                       // 16*16*32 f32
    unsigned short* catb16 = (unsigned short*)(a32buf + 8192);   // 65536*96 bf16
    unsigned short* Gbuf = catb16 + 6291456;                     // 65536*128 bf16
    short* w1p = (short*)(Gbuf + 8388608);                // 16384 bf16
    short* w0fp = w1p + 16384;                            // 12288 bf16
    short* wfp = w0fp + 12288;                            // 82944 bf16
    float* corrbuf = (float*)(wfp + 82944);               // 16*128 f32

    k_pack2<<<112, 256, 0, stream>>>(mw0, mw1, w1p, w0fp);
    k_packf<<<324, 256, 0, stream>>>(wf, wfp);
    k_corr<<<8, 256, 0, stream>>>(mw0, mb0, corrbuf);
    k_branch<128><<<2048, 256, 0, stream>>>(feats4, w4, s4, b4, a4buf, 16384);
    k_branch<256><<<32, 256, 0, stream>>>(feats32, w32, s32, b32, a32buf, 256);
    k_cat<<<8192, 256, 0, stream>>>(feats2, w2, s2, b2, a4buf, a32buf, catb16);
    k_fuseG<<<1024, 256, 0, stream>>>(catb16, wfp, sf, bf, w0fp, Gbuf);
    k_mlp7<<<4096, 256, 0, stream>>>(Gbuf, corrbuf, w1p, mb1, mw2, mb2,
                                     (float*)d_out);
}